// Round 6
// baseline (99.760 us; speedup 1.0000x reference)
//
#include <hip/hip_runtime.h>
#include <math.h>

typedef short bf16x8 __attribute__((ext_vector_type(8)));
typedef float f32x16 __attribute__((ext_vector_type(16)));

// round-to-nearest-even fp32 -> bf16 (bits)
static __device__ __forceinline__ unsigned short f2bf(float x) {
    unsigned u = __builtin_bit_cast(unsigned, x);
    unsigned r = (u + 0x7FFFu + ((u >> 16) & 1u)) >> 16;
    return (unsigned short)r;
}
static __device__ __forceinline__ float bf2f(unsigned short h) {
    unsigned u = (unsigned)h << 16;
    return __builtin_bit_cast(float, u);
}

// Kernel 1: per point p build MFMA K-vectors (bf16, hi/lo split) for two grams:
//   gram1: denom = 1 + s_i + s_j - 2<c_i,c_j>
//   gram2: dot   = <n_i,n_j>
// scattered into 32x32x16 A/B fragment layout (verified in R5: absmax 0.0):
//   point p -> tile=p>>5, m=p&31; k0..7 chunk -> lane m, k8..15 -> lane 32+m.
// Targets carry NEGATED normals (folds e_ss - 2 e_st + e_tt into one sum).
__global__ void dc_pack(const float* __restrict__ verts,
                        const float* __restrict__ tnorm,
                        const float* __restrict__ tcent,
                        const int* __restrict__ idx,
                        unsigned short* __restrict__ ws,
                        float* __restrict__ out,
                        int N, int M) {
    int p = blockIdx.x * blockDim.x + threadIdx.x;
    if (p == 0) out[0] = 0.0f;
    int P = N + M;
    if (p >= P) return;

    float cx, cy, cz, nx, ny, nz;
    if (p < N) {
        int i0 = idx[3 * p + 0], i1 = idx[3 * p + 1], i2 = idx[3 * p + 2];
        float ax = verts[3 * i0], ay = verts[3 * i0 + 1], az = verts[3 * i0 + 2];
        float bx = verts[3 * i1], by = verts[3 * i1 + 1], bz = verts[3 * i1 + 2];
        float qx = verts[3 * i2], qy = verts[3 * i2 + 1], qz = verts[3 * i2 + 2];
        float ux = ax - bx, uy = ay - by, uz = az - bz;
        float vx = qx - bx, vy = qy - by, vz = qz - bz;
        nx = 0.5f * (uy * vz - uz * vy);
        ny = 0.5f * (uz * vx - ux * vz);
        nz = 0.5f * (ux * vy - uy * vx);
        cx = (ax + bx + qx) * (1.0f / 3.0f);
        cy = (ay + by + qy) * (1.0f / 3.0f);
        cz = (az + bz + qz) * (1.0f / 3.0f);
    } else {
        int t = p - N;
        cx = tcent[3 * t]; cy = tcent[3 * t + 1]; cz = tcent[3 * t + 2];
        nx = -tnorm[3 * t]; ny = -tnorm[3 * t + 1]; nz = -tnorm[3 * t + 2];
    }

    unsigned short chx = f2bf(cx), chy = f2bf(cy), chz = f2bf(cz);
    unsigned short clx = f2bf(cx - bf2f(chx));
    unsigned short cly = f2bf(cy - bf2f(chy));
    unsigned short clz = f2bf(cz - bf2f(chz));
    unsigned short nhx = f2bf(nx), nhy = f2bf(ny), nhz = f2bf(nz);
    unsigned short nlx = f2bf(nx - bf2f(nhx));
    unsigned short nly = f2bf(ny - bf2f(nhy));
    unsigned short nlz = f2bf(nz - bf2f(nhz));
    float ex = bf2f(chx) + bf2f(clx);
    float ey = bf2f(chy) + bf2f(cly);
    float ez = bf2f(chz) + bf2f(clz);
    float s = ex * ex + ey * ey + ez * ez;
    unsigned short sh = f2bf(s), sl = f2bf(s - bf2f(sh));
    unsigned short m2hx = f2bf(-2.0f * bf2f(chx)), m2hy = f2bf(-2.0f * bf2f(chy)), m2hz = f2bf(-2.0f * bf2f(chz));
    unsigned short m2lx = f2bf(-2.0f * bf2f(clx)), m2ly = f2bf(-2.0f * bf2f(cly)), m2lz = f2bf(-2.0f * bf2f(clz));
    const unsigned short one = 0x3F80;

    __align__(16) unsigned short A1v[16] = {
        m2hx, m2hy, m2hz,  m2hx, m2hy, m2hz,  m2lx, m2ly, m2lz,
        sh, sl,  one, one,  one,  0, 0 };
    __align__(16) unsigned short B1v[16] = {
        chx, chy, chz,  clx, cly, clz,  chx, chy, chz,
        one, one,  sh, sl,  one,  0, 0 };
    __align__(16) unsigned short A2v[16] = {
        nhx, nhy, nhz,  nhx, nhy, nhz,  nlx, nly, nlz,
        0, 0, 0, 0, 0, 0, 0 };
    __align__(16) unsigned short B2v[16] = {
        nhx, nhy, nhz,  nlx, nly, nlz,  nhx, nhy, nhz,
        0, 0, 0, 0, 0, 0, 0 };

    size_t arr = (size_t)P * 16;
    unsigned short* A1 = ws;
    unsigned short* B1 = ws + arr;
    unsigned short* A2 = ws + 2 * arr;
    unsigned short* B2 = ws + 3 * arr;

    int tile = p >> 5, m = p & 31;
    size_t lo = ((size_t)tile * 64 + m) * 8;
    size_t hi = lo + 32 * 8;

    *(uint4*)(A1 + lo) = *(const uint4*)&A1v[0];
    *(uint4*)(A1 + hi) = *(const uint4*)&A1v[8];
    *(uint4*)(B1 + lo) = *(const uint4*)&B1v[0];
    *(uint4*)(B1 + hi) = *(const uint4*)&B1v[8];
    *(uint4*)(A2 + lo) = *(const uint4*)&A2v[0];
    *(uint4*)(A2 + hi) = *(const uint4*)&A2v[8];
    *(uint4*)(B2 + lo) = *(const uint4*)&B2v[0];
    *(uint4*)(B2 + hi) = *(const uint4*)&B2v[8];
}

static __device__ __forceinline__ void acc_full(f32x16& part, const f32x16& d1, const f32x16& d2) {
#pragma unroll
    for (int r = 0; r < 16; ++r)
        part[r] = fmaf(__builtin_amdgcn_rcpf(d1[r]), d2[r], part[r]);
}
static __device__ __forceinline__ void acc_half(f32x16& part, const f32x16& d1, const f32x16& d2) {
#pragma unroll
    for (int r = 0; r < 16; ++r)
        part[r] = fmaf(0.5f * __builtin_amdgcn_rcpf(d1[r]), d2[r], part[r]);
}

// Kernel 2: triangular sweep over 64x64-point SUPER-tile pairs (S <= T).
// Each super-pair = 2x2 MFMA 32-tiles: 4 B-frag loads serve 4 tile-pairs
// (halves L2 traffic). Off-diagonal tile-pairs accumulate at weight 1 and the
// final sum is doubled (covers the transpose); diagonal 32-tiles (S==T combos
// (0,0),(1,1)) are pre-halved so the final doubling restores weight 1; combo
// (1,0) at S==T is skipped (mirror of (0,1)). Total work = 50.1% of R5.
__global__ __launch_bounds__(256, 5) void dc_pair_mfma(
    const unsigned short* __restrict__ ws, float* __restrict__ out,
    int P, int W, int Tt) {
    __shared__ float wsum[4];

    const int nS = P >> 6;                        // 256 super-tiles
    size_t arr = (size_t)P * 16;
    const unsigned short* A1 = ws;
    const unsigned short* B1 = ws + arr;
    const unsigned short* A2 = ws + 2 * arr;
    const unsigned short* B2 = ws + 3 * arr;

    int tid = threadIdx.x;
    int lane = tid & 63, wv = tid >> 6;
    int wgid = blockIdx.x * 4 + wv;

    int q = Tt / W, r = Tt % W;
    int start = wgid * q + (wgid < r ? wgid : r);
    int cnt = q + (wgid < r ? 1 : 0);

    // initial row S from closed form + integer fixup; Ti = column super-index
    double dn = (double)(2 * nS + 1);
    int S = (int)((dn - sqrt(dn * dn - 8.0 * (double)start)) * 0.5);
    if (S >= nS) S = nS - 1;
    if (S < 0) S = 0;
#define CUM(s) ((s) * nS - ((s) * ((s) - 1)) / 2)
    while (S > 0 && CUM(S) > start) --S;
    while (CUM(S + 1) <= start) ++S;
    int Ti = S + (start - CUM(S));
#undef CUM

    const f32x16 zero = {0.f,0.f,0.f,0.f,0.f,0.f,0.f,0.f,0.f,0.f,0.f,0.f,0.f,0.f,0.f,0.f};
    f32x16 part = zero;

    // A fragments for the 2 row 32-tiles of super-row S (reloaded on row change)
    bf16x8 a1_0 = *(const bf16x8*)(A1 + ((size_t)(2 * S) * 64 + lane) * 8);
    bf16x8 a1_1 = *(const bf16x8*)(A1 + ((size_t)(2 * S + 1) * 64 + lane) * 8);
    bf16x8 a2_0 = *(const bf16x8*)(A2 + ((size_t)(2 * S) * 64 + lane) * 8);
    bf16x8 a2_1 = *(const bf16x8*)(A2 + ((size_t)(2 * S + 1) * 64 + lane) * 8);

    for (int it = 0; it < cnt; ++it) {
        int J = 2 * Ti;
        bf16x8 b1_0 = *(const bf16x8*)(B1 + ((size_t)J * 64 + lane) * 8);
        bf16x8 b1_1 = *(const bf16x8*)(B1 + ((size_t)(J + 1) * 64 + lane) * 8);
        bf16x8 b2_0 = *(const bf16x8*)(B2 + ((size_t)J * 64 + lane) * 8);
        bf16x8 b2_1 = *(const bf16x8*)(B2 + ((size_t)(J + 1) * 64 + lane) * 8);
        bool diag = (Ti == S);                     // wave-uniform

        f32x16 d1, d2;
        // combo (0,0)
        d1 = __builtin_amdgcn_mfma_f32_32x32x16_bf16(a1_0, b1_0, zero, 0, 0, 0);
        d2 = __builtin_amdgcn_mfma_f32_32x32x16_bf16(a2_0, b2_0, zero, 0, 0, 0);
        if (diag) acc_half(part, d1, d2); else acc_full(part, d1, d2);
        // combo (0,1)
        d1 = __builtin_amdgcn_mfma_f32_32x32x16_bf16(a1_0, b1_1, zero, 0, 0, 0);
        d2 = __builtin_amdgcn_mfma_f32_32x32x16_bf16(a2_0, b2_1, zero, 0, 0, 0);
        acc_full(part, d1, d2);
        // combo (1,0) -- mirror of (0,1) when diag: skip
        if (!diag) {
            d1 = __builtin_amdgcn_mfma_f32_32x32x16_bf16(a1_1, b1_0, zero, 0, 0, 0);
            d2 = __builtin_amdgcn_mfma_f32_32x32x16_bf16(a2_1, b2_0, zero, 0, 0, 0);
            acc_full(part, d1, d2);
        }
        // combo (1,1)
        d1 = __builtin_amdgcn_mfma_f32_32x32x16_bf16(a1_1, b1_1, zero, 0, 0, 0);
        d2 = __builtin_amdgcn_mfma_f32_32x32x16_bf16(a2_1, b2_1, zero, 0, 0, 0);
        if (diag) acc_half(part, d1, d2); else acc_full(part, d1, d2);

        // advance along the row; on row end, move to next diagonal start
        ++Ti;
        if (Ti >= nS && (it + 1) < cnt) {
            ++S; Ti = S;
            a1_0 = *(const bf16x8*)(A1 + ((size_t)(2 * S) * 64 + lane) * 8);
            a1_1 = *(const bf16x8*)(A1 + ((size_t)(2 * S + 1) * 64 + lane) * 8);
            a2_0 = *(const bf16x8*)(A2 + ((size_t)(2 * S) * 64 + lane) * 8);
            a2_1 = *(const bf16x8*)(A2 + ((size_t)(2 * S + 1) * 64 + lane) * 8);
        }
    }

    float s = 0.0f;
#pragma unroll
    for (int rr = 0; rr < 16; ++rr) s += part[rr];
    s *= 2.0f;                                     // upper triangle -> full sum
#pragma unroll
    for (int off = 32; off > 0; off >>= 1) s += __shfl_down(s, off, 64);
    if (lane == 0) wsum[wv] = s;
    __syncthreads();
    if (tid == 0) {
        float t = wsum[0] + wsum[1] + wsum[2] + wsum[3];
        atomicAdd(out, t);
    }
}

extern "C" void kernel_launch(void* const* d_in, const int* in_sizes, int n_in,
                              void* d_out, int out_size, void* d_ws, size_t ws_size,
                              hipStream_t stream) {
    const float* verts = (const float*)d_in[0];   // (V,3) f32
    const float* tnorm = (const float*)d_in[1];   // (M,3) f32
    const float* tcent = (const float*)d_in[2];   // (M,3) f32
    const int*   sidx  = (const int*)d_in[3];     // (N,3) i32

    int M = in_sizes[1] / 3;
    int N = in_sizes[3] / 3;
    int P = N + M;                                // 16384

    unsigned short* ws = (unsigned short*)d_ws;   // 4 frag arrays = 2 MB
    float* out = (float*)d_out;

    int bblocks = (P + 255) / 256;
    dc_pack<<<bblocks, 256, 0, stream>>>(verts, tnorm, tcent, sidx, ws, out, N, M);

    int nS = P >> 6;                              // 256 super-tiles
    int Tt = nS * (nS + 1) / 2;                   // 32896 super-pairs
    int nBlocks = 1280;                           // 5 blocks/CU * 256 CU: one batch
    int W = nBlocks * 4;                          // 5120 waves
    dc_pair_mfma<<<nBlocks, 256, 0, stream>>>(ws, out, P, W, Tt);
}

// Round 7
// 90.418 us; speedup vs baseline: 1.1033x; 1.1033x over previous
//
#include <hip/hip_runtime.h>

typedef short bf16x8 __attribute__((ext_vector_type(8)));
typedef float f32x16 __attribute__((ext_vector_type(16)));

// round-to-nearest-even fp32 -> bf16 (bits)
static __device__ __forceinline__ unsigned short f2bf(float x) {
    unsigned u = __builtin_bit_cast(unsigned, x);
    unsigned r = (u + 0x7FFFu + ((u >> 16) & 1u)) >> 16;
    return (unsigned short)r;
}
static __device__ __forceinline__ float bf2f(unsigned short h) {
    unsigned u = (unsigned)h << 16;
    return __builtin_bit_cast(float, u);
}

// Kernel 1: per point p build MFMA K-vectors (bf16, hi/lo split) for two grams:
//   gram1: denom = 1 + s_i + s_j - 2<c_i,c_j>
//   gram2: dot   = <n_i,n_j>
// scattered into 32x32x16 A/B fragment layout (verified R5/R6: absmax 0.0):
//   point p -> tile=p>>5, m=p&31; k0..7 chunk -> lane m, k8..15 -> lane 32+m.
// Targets carry NEGATED normals (folds e_ss - 2 e_st + e_tt into one sum).
__global__ void dc_pack(const float* __restrict__ verts,
                        const float* __restrict__ tnorm,
                        const float* __restrict__ tcent,
                        const int* __restrict__ idx,
                        unsigned short* __restrict__ ws,
                        float* __restrict__ out,
                        int N, int M) {
    int p = blockIdx.x * blockDim.x + threadIdx.x;
    if (p == 0) out[0] = 0.0f;
    int P = N + M;
    if (p >= P) return;

    float cx, cy, cz, nx, ny, nz;
    if (p < N) {
        int i0 = idx[3 * p + 0], i1 = idx[3 * p + 1], i2 = idx[3 * p + 2];
        float ax = verts[3 * i0], ay = verts[3 * i0 + 1], az = verts[3 * i0 + 2];
        float bx = verts[3 * i1], by = verts[3 * i1 + 1], bz = verts[3 * i1 + 2];
        float qx = verts[3 * i2], qy = verts[3 * i2 + 1], qz = verts[3 * i2 + 2];
        float ux = ax - bx, uy = ay - by, uz = az - bz;
        float vx = qx - bx, vy = qy - by, vz = qz - bz;
        nx = 0.5f * (uy * vz - uz * vy);
        ny = 0.5f * (uz * vx - ux * vz);
        nz = 0.5f * (ux * vy - uy * vx);
        cx = (ax + bx + qx) * (1.0f / 3.0f);
        cy = (ay + by + qy) * (1.0f / 3.0f);
        cz = (az + bz + qz) * (1.0f / 3.0f);
    } else {
        int t = p - N;
        cx = tcent[3 * t]; cy = tcent[3 * t + 1]; cz = tcent[3 * t + 2];
        nx = -tnorm[3 * t]; ny = -tnorm[3 * t + 1]; nz = -tnorm[3 * t + 2];
    }

    unsigned short chx = f2bf(cx), chy = f2bf(cy), chz = f2bf(cz);
    unsigned short clx = f2bf(cx - bf2f(chx));
    unsigned short cly = f2bf(cy - bf2f(chy));
    unsigned short clz = f2bf(cz - bf2f(chz));
    unsigned short nhx = f2bf(nx), nhy = f2bf(ny), nhz = f2bf(nz);
    unsigned short nlx = f2bf(nx - bf2f(nhx));
    unsigned short nly = f2bf(ny - bf2f(nhy));
    unsigned short nlz = f2bf(nz - bf2f(nhz));
    float ex = bf2f(chx) + bf2f(clx);
    float ey = bf2f(chy) + bf2f(cly);
    float ez = bf2f(chz) + bf2f(clz);
    float s = ex * ex + ey * ey + ez * ez;
    unsigned short sh = f2bf(s), sl = f2bf(s - bf2f(sh));
    unsigned short m2hx = f2bf(-2.0f * bf2f(chx)), m2hy = f2bf(-2.0f * bf2f(chy)), m2hz = f2bf(-2.0f * bf2f(chz));
    unsigned short m2lx = f2bf(-2.0f * bf2f(clx)), m2ly = f2bf(-2.0f * bf2f(cly)), m2lz = f2bf(-2.0f * bf2f(clz));
    const unsigned short one = 0x3F80;

    __align__(16) unsigned short A1v[16] = {
        m2hx, m2hy, m2hz,  m2hx, m2hy, m2hz,  m2lx, m2ly, m2lz,
        sh, sl,  one, one,  one,  0, 0 };
    __align__(16) unsigned short B1v[16] = {
        chx, chy, chz,  clx, cly, clz,  chx, chy, chz,
        one, one,  sh, sl,  one,  0, 0 };
    __align__(16) unsigned short A2v[16] = {
        nhx, nhy, nhz,  nhx, nhy, nhz,  nlx, nly, nlz,
        0, 0, 0, 0, 0, 0, 0 };
    __align__(16) unsigned short B2v[16] = {
        nhx, nhy, nhz,  nlx, nly, nlz,  nhx, nhy, nhz,
        0, 0, 0, 0, 0, 0, 0 };

    size_t arr = (size_t)P * 16;
    unsigned short* A1 = ws;
    unsigned short* B1 = ws + arr;
    unsigned short* A2 = ws + 2 * arr;
    unsigned short* B2 = ws + 3 * arr;

    int tile = p >> 5, m = p & 31;
    size_t lo = ((size_t)tile * 64 + m) * 8;
    size_t hi = lo + 32 * 8;

    *(uint4*)(A1 + lo) = *(const uint4*)&A1v[0];
    *(uint4*)(A1 + hi) = *(const uint4*)&A1v[8];
    *(uint4*)(B1 + lo) = *(const uint4*)&B1v[0];
    *(uint4*)(B1 + hi) = *(const uint4*)&B1v[8];
    *(uint4*)(A2 + lo) = *(const uint4*)&A2v[0];
    *(uint4*)(A2 + hi) = *(const uint4*)&A2v[8];
    *(uint4*)(B2 + lo) = *(const uint4*)&B2v[0];
    *(uint4*)(B2 + hi) = *(const uint4*)&B2v[8];
}

// 4-way batched reciprocal epilogue:
//   sum_g x_g / a_g over 4 pairs -> 1 rcp:  num/(a0 a1 a2 a3) form.
// 10 VALU + 1 rcp per 4 pairs vs 4 rcp + 4 fma. fp32 exact enough
// (denoms in [1,~1e2], products <= ~1e8).
template <bool HALF>
static __device__ __forceinline__ void acc4(float4& part, const f32x16& d1, const f32x16& d2) {
#pragma unroll
    for (int g = 0; g < 4; ++g) {
        const int r = 4 * g;
        float p01 = d1[r] * d1[r + 1];
        float p23 = d1[r + 2] * d1[r + 3];
        float n01 = fmaf(d2[r], d1[r + 1], d2[r + 1] * d1[r]);
        float n23 = fmaf(d2[r + 2], d1[r + 3], d2[r + 3] * d1[r + 2]);
        float t   = p01 * p23;
        float num = fmaf(n01, p23, n23 * p01);
        float rk  = __builtin_amdgcn_rcpf(t);
        if (HALF) rk *= 0.5f;
        (&part.x)[g] = fmaf(num, rk, (&part.x)[g]);
    }
}

// Kernel 2: circular-tile symmetric sweep (R5 streaming structure + symmetry).
// Full sum = 2 * sum_I [ 0.5*T(I,I) + sum_{d=1}^{255} T(I,I+d) + 0.5*T(I,I+256) ]
// (nT=512 tiles, indices mod nT). Each row's d-range [0,256] is split into 10
// contiguous chunks (7x26 + 3x25); wave g handles row I=g/10, chunk c=g%10.
// 5120 waves = 1280 blocks = 5 blocks/CU: one uniform batch, streaming B loads.
__global__ __launch_bounds__(256, 5) void dc_pair_mfma(
    const unsigned short* __restrict__ ws, float* __restrict__ out, int P) {
    __shared__ float wsum[4];

    const int nT = P >> 5;          // 512
    const int half = nT >> 1;       // 256
    size_t arr = (size_t)P * 16;
    const unsigned short* A1 = ws;
    const unsigned short* B1 = ws + arr;
    const unsigned short* A2 = ws + 2 * arr;
    const unsigned short* B2 = ws + 3 * arr;

    int tid = threadIdx.x;
    int lane = tid & 63, wv = tid >> 6;
    int g = blockIdx.x * 4 + wv;
    int I = g / 10;
    int c = g - 10 * I;

    int st  = c * 26 - (c > 7 ? c - 7 : 0);     // chunk start offset d
    int len = 26 - (c >= 7 ? 1 : 0);            // 7x26 + 3x25 = 257

    bf16x8 a1 = *(const bf16x8*)(A1 + ((size_t)I * 64 + lane) * 8);
    bf16x8 a2 = *(const bf16x8*)(A2 + ((size_t)I * 64 + lane) * 8);

    const f32x16 zero = {0.f,0.f,0.f,0.f,0.f,0.f,0.f,0.f,0.f,0.f,0.f,0.f,0.f,0.f,0.f,0.f};
    float4 part = make_float4(0.f, 0.f, 0.f, 0.f);

#pragma unroll 2
    for (int it = 0; it < len; ++it) {
        int d = st + it;
        int j = I + d;
        int jm = (j >= nT) ? j - nT : j;        // circular wrap (at most once)
        const bf16x8 b1 = *(const bf16x8*)(B1 + ((size_t)jm * 64 + lane) * 8);
        const bf16x8 b2 = *(const bf16x8*)(B2 + ((size_t)jm * 64 + lane) * 8);
        f32x16 d1 = __builtin_amdgcn_mfma_f32_32x32x16_bf16(a1, b1, zero, 0, 0, 0);
        f32x16 d2 = __builtin_amdgcn_mfma_f32_32x32x16_bf16(a2, b2, zero, 0, 0, 0);
        if (d == 0 || d == half) acc4<true>(part, d1, d2);   // wave-uniform branch
        else                     acc4<false>(part, d1, d2);
    }

    float s = (part.x + part.y + part.z + part.w) * 2.0f;   // triangle -> full
#pragma unroll
    for (int off = 32; off > 0; off >>= 1) s += __shfl_down(s, off, 64);
    if (lane == 0) wsum[wv] = s;
    __syncthreads();
    if (tid == 0) {
        float t = wsum[0] + wsum[1] + wsum[2] + wsum[3];
        atomicAdd(out, t);
    }
}

extern "C" void kernel_launch(void* const* d_in, const int* in_sizes, int n_in,
                              void* d_out, int out_size, void* d_ws, size_t ws_size,
                              hipStream_t stream) {
    const float* verts = (const float*)d_in[0];   // (V,3) f32
    const float* tnorm = (const float*)d_in[1];   // (M,3) f32
    const float* tcent = (const float*)d_in[2];   // (M,3) f32
    const int*   sidx  = (const int*)d_in[3];     // (N,3) i32

    int M = in_sizes[1] / 3;
    int N = in_sizes[3] / 3;
    int P = N + M;                                // 16384

    unsigned short* ws = (unsigned short*)d_ws;   // 4 frag arrays = 2 MB
    float* out = (float*)d_out;

    int bblocks = (P + 255) / 256;
    dc_pack<<<bblocks, 256, 0, stream>>>(verts, tnorm, tcent, sidx, ws, out, N, M);

    // 512 rows x 10 chunks = 5120 waves = 1280 blocks (5 blocks/CU, one batch)
    int nT = P >> 5;
    int nBlocks = (nT * 10) / 4;                  // 1280
    dc_pair_mfma<<<nBlocks, 256, 0, stream>>>(ws, out, P);
}

// Round 8
// 87.537 us; speedup vs baseline: 1.1396x; 1.0329x over previous
//
#include <hip/hip_runtime.h>

typedef short bf16x8 __attribute__((ext_vector_type(8)));
typedef float f32x16 __attribute__((ext_vector_type(16)));

// round-to-nearest-even fp32 -> bf16 (bits)
static __device__ __forceinline__ unsigned short f2bf(float x) {
    unsigned u = __builtin_bit_cast(unsigned, x);
    unsigned r = (u + 0x7FFFu + ((u >> 16) & 1u)) >> 16;
    return (unsigned short)r;
}
static __device__ __forceinline__ float bf2f(unsigned short h) {
    unsigned u = (unsigned)h << 16;
    return __builtin_bit_cast(float, u);
}

// Workspace layout (shorts): A1[P*16] | A2[P*16] | BB[P*32]
// BB interleaves the B1/B2 fragments: per (tile,lane) 16 shorts = b1(8),b2(8),
// so each lane reads 32 contiguous bytes per j-tile.

// Kernel 1: per point p build MFMA K-vectors (bf16, hi/lo split) for two grams:
//   gram1: denom = 1 + s_i + s_j - 2<c_i,c_j>;  gram2: dot = <n_i,n_j>
// 32x32x16 fragment layout (verified R5-R7, absmax 0.0): point p -> tile=p>>5,
// m=p&31; k0..7 chunk -> lane m, k8..15 -> lane 32+m.
// Targets carry NEGATED normals (folds e_ss - 2 e_st + e_tt into one sum).
__global__ void dc_pack(const float* __restrict__ verts,
                        const float* __restrict__ tnorm,
                        const float* __restrict__ tcent,
                        const int* __restrict__ idx,
                        unsigned short* __restrict__ ws,
                        float* __restrict__ out,
                        int N, int M) {
    int p = blockIdx.x * blockDim.x + threadIdx.x;
    if (p == 0) out[0] = 0.0f;
    int P = N + M;
    if (p >= P) return;

    float cx, cy, cz, nx, ny, nz;
    if (p < N) {
        int i0 = idx[3 * p + 0], i1 = idx[3 * p + 1], i2 = idx[3 * p + 2];
        float ax = verts[3 * i0], ay = verts[3 * i0 + 1], az = verts[3 * i0 + 2];
        float bx = verts[3 * i1], by = verts[3 * i1 + 1], bz = verts[3 * i1 + 2];
        float qx = verts[3 * i2], qy = verts[3 * i2 + 1], qz = verts[3 * i2 + 2];
        float ux = ax - bx, uy = ay - by, uz = az - bz;
        float vx = qx - bx, vy = qy - by, vz = qz - bz;
        nx = 0.5f * (uy * vz - uz * vy);
        ny = 0.5f * (uz * vx - ux * vz);
        nz = 0.5f * (ux * vy - uy * vx);
        cx = (ax + bx + qx) * (1.0f / 3.0f);
        cy = (ay + by + qy) * (1.0f / 3.0f);
        cz = (az + bz + qz) * (1.0f / 3.0f);
    } else {
        int t = p - N;
        cx = tcent[3 * t]; cy = tcent[3 * t + 1]; cz = tcent[3 * t + 2];
        nx = -tnorm[3 * t]; ny = -tnorm[3 * t + 1]; nz = -tnorm[3 * t + 2];
    }

    unsigned short chx = f2bf(cx), chy = f2bf(cy), chz = f2bf(cz);
    unsigned short clx = f2bf(cx - bf2f(chx));
    unsigned short cly = f2bf(cy - bf2f(chy));
    unsigned short clz = f2bf(cz - bf2f(chz));
    unsigned short nhx = f2bf(nx), nhy = f2bf(ny), nhz = f2bf(nz);
    unsigned short nlx = f2bf(nx - bf2f(nhx));
    unsigned short nly = f2bf(ny - bf2f(nhy));
    unsigned short nlz = f2bf(nz - bf2f(nhz));
    float ex = bf2f(chx) + bf2f(clx);
    float ey = bf2f(chy) + bf2f(cly);
    float ez = bf2f(chz) + bf2f(clz);
    float s = ex * ex + ey * ey + ez * ez;
    unsigned short sh = f2bf(s), sl = f2bf(s - bf2f(sh));
    unsigned short m2hx = f2bf(-2.0f * bf2f(chx)), m2hy = f2bf(-2.0f * bf2f(chy)), m2hz = f2bf(-2.0f * bf2f(chz));
    unsigned short m2lx = f2bf(-2.0f * bf2f(clx)), m2ly = f2bf(-2.0f * bf2f(cly)), m2lz = f2bf(-2.0f * bf2f(clz));
    const unsigned short one = 0x3F80;

    __align__(16) unsigned short A1v[16] = {
        m2hx, m2hy, m2hz,  m2hx, m2hy, m2hz,  m2lx, m2ly, m2lz,
        sh, sl,  one, one,  one,  0, 0 };
    __align__(16) unsigned short B1v[16] = {
        chx, chy, chz,  clx, cly, clz,  chx, chy, chz,
        one, one,  sh, sl,  one,  0, 0 };
    __align__(16) unsigned short A2v[16] = {
        nhx, nhy, nhz,  nhx, nhy, nhz,  nlx, nly, nlz,
        0, 0, 0, 0, 0, 0, 0 };
    __align__(16) unsigned short B2v[16] = {
        nhx, nhy, nhz,  nlx, nly, nlz,  nhx, nhy, nhz,
        0, 0, 0, 0, 0, 0, 0 };

    size_t arr = (size_t)P * 16;
    unsigned short* A1 = ws;
    unsigned short* A2 = ws + arr;
    unsigned short* BB = ws + 2 * arr;

    int tile = p >> 5, m = p & 31;
    size_t lo = ((size_t)tile * 64 + m) * 8;       // k0..7 -> lane m
    size_t hi = lo + 32 * 8;                       // k8..15 -> lane 32+m

    *(uint4*)(A1 + lo) = *(const uint4*)&A1v[0];
    *(uint4*)(A1 + hi) = *(const uint4*)&A1v[8];
    *(uint4*)(A2 + lo) = *(const uint4*)&A2v[0];
    *(uint4*)(A2 + hi) = *(const uint4*)&A2v[8];

    size_t blo = ((size_t)tile * 64 + m) * 16;     // interleaved b1|b2
    size_t bhi = ((size_t)tile * 64 + 32 + m) * 16;
    *(uint4*)(BB + blo)     = *(const uint4*)&B1v[0];
    *(uint4*)(BB + blo + 8) = *(const uint4*)&B2v[0];
    *(uint4*)(BB + bhi)     = *(const uint4*)&B1v[8];
    *(uint4*)(BB + bhi + 8) = *(const uint4*)&B2v[8];
}

// 4-way batched reciprocal: sum of 4 x/a terms via 1 rcp. ~10 VALU + 1 trans
// per 4 pairs. fp32-exact enough (denoms in [1,1e2], products <= 1e8).
static __device__ __forceinline__ void acc4(float4& part, const f32x16& d1, const f32x16& d2) {
#pragma unroll
    for (int g = 0; g < 4; ++g) {
        const int r = 4 * g;
        float p01 = d1[r] * d1[r + 1];
        float p23 = d1[r + 2] * d1[r + 3];
        float n01 = fmaf(d2[r], d1[r + 1], d2[r + 1] * d1[r]);
        float n23 = fmaf(d2[r + 2], d1[r + 3], d2[r + 3] * d1[r + 2]);
        float t   = p01 * p23;
        float num = fmaf(n01, p23, n23 * p01);
        (&part.x)[g] = fmaf(num, __builtin_amdgcn_rcpf(t), (&part.x)[g]);
    }
}

// Kernel 2: branch-free circular-tile symmetric sweep.
//   S = sum_I sum_{d=0..256} T(I, (I+d) mod nT);  D = sum_I [T(I,I)+T(I,I+256)]
//   full = 2S - D  =>  per wave: s = 2*partA + partB  (partB holds its D tiles)
// Row I's d-range [1,255] is split into 10 wave-uniform chunks; the c=0 wave
// also does d=0 into partB, the c=9 wave d=256 into partB. Inner loops are
// branch-free with unconditional one-ahead prefetch (pointer increment), so
// the compiler can pipeline B loads across iterations (the R5 property that
// R6/R7's in-loop branches destroyed). 1280 blocks = 5/CU, one uniform batch.
__global__ __launch_bounds__(256, 5) void dc_pair_mfma(
    const unsigned short* __restrict__ ws, float* __restrict__ out, int P) {
    __shared__ float wsum[4];

    const int nT = P >> 5;                     // 512
    size_t arr = (size_t)P * 16;
    const unsigned short* A1 = ws;
    const unsigned short* A2 = ws + arr;
    const unsigned short* BB = ws + 2 * arr;

    int tid = threadIdx.x;
    int lane = tid & 63, wv = tid >> 6;
    int g = blockIdx.x * 4 + wv;
    int I = g / 10;
    int c = g - 10 * I;

    // chunk map over d in [1,255]: c0:1..25, c1..c6: 26 each, c7,c8: 25, c9: 232..255
    int st  = c * 26 - (c > 7 ? c - 7 : 0);
    int len = 26 - (c >= 7 ? 1 : 0);
    int d0 = st, L = len, extra = 0, extraTile = 0;
    if (c == 0) { d0 = 1; L = 25; extra = 1; extraTile = I; }
    else if (c == 9) { L = 24; extra = 1;
        extraTile = I + 256 - ((I + 256 >= nT) ? nT : 0); }

    bf16x8 a1 = *(const bf16x8*)(A1 + ((size_t)I * 64 + lane) * 8);
    bf16x8 a2 = *(const bf16x8*)(A2 + ((size_t)I * 64 + lane) * 8);

    const f32x16 zero = {0.f,0.f,0.f,0.f,0.f,0.f,0.f,0.f,0.f,0.f,0.f,0.f,0.f,0.f,0.f,0.f};
    float4 partA = make_float4(0.f, 0.f, 0.f, 0.f);
    float4 partB = make_float4(0.f, 0.f, 0.f, 0.f);

    // segment split at the circular wrap (at most one wrap: I + d <= 767)
    int js   = I + d0;
    int len1 = nT - js; if (len1 > L) len1 = L; if (len1 < 0) len1 = 0;
    int len2 = L - len1;
    int startA = (len1 > 0) ? js : js - nT;

    const size_t laneOff = (size_t)lane * 16;

    // --- segment 1 (pre-wrap), branch-free pipelined ---
    {
        const unsigned short* pb = BB + (size_t)startA * 1024 + laneOff;
        bf16x8 b1 = *(const bf16x8*)pb;
        bf16x8 b2 = *(const bf16x8*)(pb + 8);
#pragma unroll 2
        for (int it = 0; it < len1; ++it) {
            pb += 1024;
            bf16x8 nb1 = *(const bf16x8*)pb;        // unconditional prefetch
            bf16x8 nb2 = *(const bf16x8*)(pb + 8);  // (overrun lands in ws slack)
            f32x16 d1 = __builtin_amdgcn_mfma_f32_32x32x16_bf16(a1, b1, zero, 0, 0, 0);
            f32x16 d2 = __builtin_amdgcn_mfma_f32_32x32x16_bf16(a2, b2, zero, 0, 0, 0);
            acc4(partA, d1, d2);
            b1 = nb1; b2 = nb2;
        }
    }
    // --- segment 2 (post-wrap), wave-uniform guard outside the hot loop ---
    if (len2 > 0) {
        const unsigned short* pb = BB + (size_t)(js + len1 - nT) * 1024 + laneOff;
        bf16x8 b1 = *(const bf16x8*)pb;
        bf16x8 b2 = *(const bf16x8*)(pb + 8);
#pragma unroll 2
        for (int it = 0; it < len2; ++it) {
            pb += 1024;
            bf16x8 nb1 = *(const bf16x8*)pb;
            bf16x8 nb2 = *(const bf16x8*)(pb + 8);
            f32x16 d1 = __builtin_amdgcn_mfma_f32_32x32x16_bf16(a1, b1, zero, 0, 0, 0);
            f32x16 d2 = __builtin_amdgcn_mfma_f32_32x32x16_bf16(a2, b2, zero, 0, 0, 0);
            acc4(partA, d1, d2);
            b1 = nb1; b2 = nb2;
        }
    }
    // --- D tiles (d=0 or d=256), 0/1-trip, into partB ---
    for (int e = 0; e < extra; ++e) {
        const unsigned short* pb = BB + (size_t)extraTile * 1024 + laneOff;
        bf16x8 b1 = *(const bf16x8*)pb;
        bf16x8 b2 = *(const bf16x8*)(pb + 8);
        f32x16 d1 = __builtin_amdgcn_mfma_f32_32x32x16_bf16(a1, b1, zero, 0, 0, 0);
        f32x16 d2 = __builtin_amdgcn_mfma_f32_32x32x16_bf16(a2, b2, zero, 0, 0, 0);
        acc4(partB, d1, d2);
    }

    // full = 2S - D  =>  s = 2*partA + partB
    float s = 2.0f * (partA.x + partA.y + partA.z + partA.w)
            + (partB.x + partB.y + partB.z + partB.w);
#pragma unroll
    for (int off = 32; off > 0; off >>= 1) s += __shfl_down(s, off, 64);
    if (lane == 0) wsum[wv] = s;
    __syncthreads();
    if (tid == 0) {
        float t = wsum[0] + wsum[1] + wsum[2] + wsum[3];
        atomicAdd(out, t);
    }
}

extern "C" void kernel_launch(void* const* d_in, const int* in_sizes, int n_in,
                              void* d_out, int out_size, void* d_ws, size_t ws_size,
                              hipStream_t stream) {
    const float* verts = (const float*)d_in[0];   // (V,3) f32
    const float* tnorm = (const float*)d_in[1];   // (M,3) f32
    const float* tcent = (const float*)d_in[2];   // (M,3) f32
    const int*   sidx  = (const int*)d_in[3];     // (N,3) i32

    int M = in_sizes[1] / 3;
    int N = in_sizes[3] / 3;
    int P = N + M;                                // 16384

    unsigned short* ws = (unsigned short*)d_ws;   // A1|A2|BB = 2 MB of 268 MB
    float* out = (float*)d_out;

    int bblocks = (P + 255) / 256;
    dc_pack<<<bblocks, 256, 0, stream>>>(verts, tnorm, tcent, sidx, ws, out, N, M);

    // 512 rows x 10 chunks = 5120 waves = 1280 blocks (5 blocks/CU, one batch)
    int nT = P >> 5;
    int nBlocks = (nT * 10) / 4;                  // 1280
    dc_pair_mfma<<<nBlocks, 256, 0, stream>>>(ws, out, P);
}

// Round 9
// 83.752 us; speedup vs baseline: 1.1911x; 1.0452x over previous
//
#include <hip/hip_runtime.h>

typedef short bf16x8 __attribute__((ext_vector_type(8)));
typedef float f32x16 __attribute__((ext_vector_type(16)));

// round-to-nearest-even fp32 -> bf16 (bits)
static __device__ __forceinline__ unsigned short f2bf(float x) {
    unsigned u = __builtin_bit_cast(unsigned, x);
    unsigned r = (u + 0x7FFFu + ((u >> 16) & 1u)) >> 16;
    return (unsigned short)r;
}
static __device__ __forceinline__ float bf2f(unsigned short h) {
    unsigned u = (unsigned)h << 16;
    return __builtin_bit_cast(float, u);
}

// Workspace (shorts): A1[P*16] | A2[P*16] | B1[P*16] | B2[P*16]  (separate
// arrays: every frag load is a fully-coalesced dwordx4 = 16 line-requests;
// R8's interleaved layout doubled TA requests -> reverted).

// Kernel 1: per point p build MFMA K-vectors (bf16, hi/lo split) for two grams:
//   gram1: denom = 1 + s_i + s_j - 2<c_i,c_j>;  gram2: dot = <n_i,n_j>
// 32x32x16 fragment layout (verified R5-R8, absmax 0.0): point p -> tile=p>>5,
// m=p&31; k0..7 chunk -> lane m, k8..15 -> lane 32+m.
// Targets carry NEGATED normals (folds e_ss - 2 e_st + e_tt into one sum).
__global__ void dc_pack(const float* __restrict__ verts,
                        const float* __restrict__ tnorm,
                        const float* __restrict__ tcent,
                        const int* __restrict__ idx,
                        unsigned short* __restrict__ ws,
                        float* __restrict__ out,
                        int N, int M) {
    int p = blockIdx.x * blockDim.x + threadIdx.x;
    if (p == 0) out[0] = 0.0f;
    int P = N + M;
    if (p >= P) return;

    float cx, cy, cz, nx, ny, nz;
    if (p < N) {
        int i0 = idx[3 * p + 0], i1 = idx[3 * p + 1], i2 = idx[3 * p + 2];
        float ax = verts[3 * i0], ay = verts[3 * i0 + 1], az = verts[3 * i0 + 2];
        float bx = verts[3 * i1], by = verts[3 * i1 + 1], bz = verts[3 * i1 + 2];
        float qx = verts[3 * i2], qy = verts[3 * i2 + 1], qz = verts[3 * i2 + 2];
        float ux = ax - bx, uy = ay - by, uz = az - bz;
        float vx = qx - bx, vy = qy - by, vz = qz - bz;
        nx = 0.5f * (uy * vz - uz * vy);
        ny = 0.5f * (uz * vx - ux * vz);
        nz = 0.5f * (ux * vy - uy * vx);
        cx = (ax + bx + qx) * (1.0f / 3.0f);
        cy = (ay + by + qy) * (1.0f / 3.0f);
        cz = (az + bz + qz) * (1.0f / 3.0f);
    } else {
        int t = p - N;
        cx = tcent[3 * t]; cy = tcent[3 * t + 1]; cz = tcent[3 * t + 2];
        nx = -tnorm[3 * t]; ny = -tnorm[3 * t + 1]; nz = -tnorm[3 * t + 2];
    }

    unsigned short chx = f2bf(cx), chy = f2bf(cy), chz = f2bf(cz);
    unsigned short clx = f2bf(cx - bf2f(chx));
    unsigned short cly = f2bf(cy - bf2f(chy));
    unsigned short clz = f2bf(cz - bf2f(chz));
    unsigned short nhx = f2bf(nx), nhy = f2bf(ny), nhz = f2bf(nz);
    unsigned short nlx = f2bf(nx - bf2f(nhx));
    unsigned short nly = f2bf(ny - bf2f(nhy));
    unsigned short nlz = f2bf(nz - bf2f(nhz));
    float ex = bf2f(chx) + bf2f(clx);
    float ey = bf2f(chy) + bf2f(cly);
    float ez = bf2f(chz) + bf2f(clz);
    float s = ex * ex + ey * ey + ez * ez;
    unsigned short sh = f2bf(s), sl = f2bf(s - bf2f(sh));
    unsigned short m2hx = f2bf(-2.0f * bf2f(chx)), m2hy = f2bf(-2.0f * bf2f(chy)), m2hz = f2bf(-2.0f * bf2f(chz));
    unsigned short m2lx = f2bf(-2.0f * bf2f(clx)), m2ly = f2bf(-2.0f * bf2f(cly)), m2lz = f2bf(-2.0f * bf2f(clz));
    const unsigned short one = 0x3F80;

    __align__(16) unsigned short A1v[16] = {
        m2hx, m2hy, m2hz,  m2hx, m2hy, m2hz,  m2lx, m2ly, m2lz,
        sh, sl,  one, one,  one,  0, 0 };
    __align__(16) unsigned short B1v[16] = {
        chx, chy, chz,  clx, cly, clz,  chx, chy, chz,
        one, one,  sh, sl,  one,  0, 0 };
    __align__(16) unsigned short A2v[16] = {
        nhx, nhy, nhz,  nhx, nhy, nhz,  nlx, nly, nlz,
        0, 0, 0, 0, 0, 0, 0 };
    __align__(16) unsigned short B2v[16] = {
        nhx, nhy, nhz,  nlx, nly, nlz,  nhx, nhy, nhz,
        0, 0, 0, 0, 0, 0, 0 };

    size_t arr = (size_t)P * 16;
    unsigned short* A1 = ws;
    unsigned short* A2 = ws + arr;
    unsigned short* B1 = ws + 2 * arr;
    unsigned short* B2 = ws + 3 * arr;

    int tile = p >> 5, m = p & 31;
    size_t lo = ((size_t)tile * 64 + m) * 8;       // k0..7 -> lane m
    size_t hi = lo + 32 * 8;                       // k8..15 -> lane 32+m

    *(uint4*)(A1 + lo) = *(const uint4*)&A1v[0];
    *(uint4*)(A1 + hi) = *(const uint4*)&A1v[8];
    *(uint4*)(A2 + lo) = *(const uint4*)&A2v[0];
    *(uint4*)(A2 + hi) = *(const uint4*)&A2v[8];
    *(uint4*)(B1 + lo) = *(const uint4*)&B1v[0];
    *(uint4*)(B1 + hi) = *(const uint4*)&B1v[8];
    *(uint4*)(B2 + lo) = *(const uint4*)&B2v[0];
    *(uint4*)(B2 + hi) = *(const uint4*)&B2v[8];
}

// 4-way batched reciprocal: sum of 4 x/a terms via 1 rcp (trans-pipe 4x cut).
static __device__ __forceinline__ void acc4(float4& part, const f32x16& d1, const f32x16& d2) {
#pragma unroll
    for (int g = 0; g < 4; ++g) {
        const int r = 4 * g;
        float p01 = d1[r] * d1[r + 1];
        float p23 = d1[r + 2] * d1[r + 3];
        float n01 = fmaf(d2[r], d1[r + 1], d2[r + 1] * d1[r]);
        float n23 = fmaf(d2[r + 2], d1[r + 3], d2[r + 3] * d1[r + 2]);
        float t   = p01 * p23;
        float num = fmaf(n01, p23, n23 * p01);
        (&part.x)[g] = fmaf(num, __builtin_amdgcn_rcpf(t), (&part.x)[g]);
    }
}

// Kernel 2: row-paired circular symmetric sweep.
// Rows (I0=2rp, I1=I0+1) share j-window W=[I0+1, I0+256] (mod nT). Exact:
//   contrib(rp) = 2*sum_W [T(I0,j)+T(I1,j)]
//               + T(I0,I0) + T(I1,I0+257) - T(I0,I0+256) - T(I1,I0+1)
// Each B-frag load feeds 4 MFMAs (2 rows x 2 grams): VMEM requests per
// tile-unit drop 4x vs R8 (the R5-R8 limiter). 256 rp x 16 chunks = 4096
// waves = 1024 blocks = 4/CU, one uniform batch. Hot loop branch-free with
// one-ahead prefetch; edge tiles on chunk-0/15 waves outside the loop.
__global__ __launch_bounds__(256, 4) void dc_pair_mfma(
    const unsigned short* __restrict__ ws, float* __restrict__ out, int P) {
    __shared__ float wsum[4];

    const int nT = P >> 5;                     // 512
    size_t arr = (size_t)P * 16;
    const unsigned short* A1 = ws;
    const unsigned short* A2 = ws + arr;
    const unsigned short* B1 = ws + 2 * arr;
    const unsigned short* B2 = ws + 3 * arr;

    int tid = threadIdx.x;
    int lane = tid & 63, wv = tid >> 6;
    int gi = blockIdx.x * 4 + wv;              // 0..4095
    int rp = gi >> 4, c = gi & 15;
    int I0 = 2 * rp, I1 = I0 + 1;

    const size_t lo = (size_t)lane * 8;

    bf16x8 a1_0 = *(const bf16x8*)(A1 + (size_t)I0 * 512 + lo);
    bf16x8 a2_0 = *(const bf16x8*)(A2 + (size_t)I0 * 512 + lo);
    bf16x8 a1_1 = *(const bf16x8*)(A1 + (size_t)I1 * 512 + lo);
    bf16x8 a2_1 = *(const bf16x8*)(A2 + (size_t)I1 * 512 + lo);

    const f32x16 zero = {0.f,0.f,0.f,0.f,0.f,0.f,0.f,0.f,0.f,0.f,0.f,0.f,0.f,0.f,0.f,0.f};
    float4 partA = make_float4(0.f, 0.f, 0.f, 0.f);
    float4 corrP = make_float4(0.f, 0.f, 0.f, 0.f);
    float4 corrM = make_float4(0.f, 0.f, 0.f, 0.f);

    auto run = [&](int startTile, int n) {
        const unsigned short* p1 = B1 + (size_t)startTile * 512 + lo;
        const unsigned short* p2 = B2 + (size_t)startTile * 512 + lo;
        bf16x8 b1 = *(const bf16x8*)p1;
        bf16x8 b2 = *(const bf16x8*)p2;
        for (int it = 0; it < n; ++it) {
            p1 += 512; p2 += 512;
            bf16x8 nb1 = *(const bf16x8*)p1;    // unconditional prefetch
            bf16x8 nb2 = *(const bf16x8*)p2;    // (overrun stays inside ws)
            f32x16 d1 = __builtin_amdgcn_mfma_f32_32x32x16_bf16(a1_0, b1, zero, 0, 0, 0);
            f32x16 d2 = __builtin_amdgcn_mfma_f32_32x32x16_bf16(a2_0, b2, zero, 0, 0, 0);
            acc4(partA, d1, d2);
            d1 = __builtin_amdgcn_mfma_f32_32x32x16_bf16(a1_1, b1, zero, 0, 0, 0);
            d2 = __builtin_amdgcn_mfma_f32_32x32x16_bf16(a2_1, b2, zero, 0, 0, 0);
            acc4(partA, d1, d2);
            b1 = nb1; b2 = nb2;
        }
    };
    auto one_tile = [&](float4& part, const bf16x8& x1, const bf16x8& x2, int jm) {
        const bf16x8 b1 = *(const bf16x8*)(B1 + (size_t)jm * 512 + lo);
        const bf16x8 b2 = *(const bf16x8*)(B2 + (size_t)jm * 512 + lo);
        f32x16 d1 = __builtin_amdgcn_mfma_f32_32x32x16_bf16(x1, b1, zero, 0, 0, 0);
        f32x16 d2 = __builtin_amdgcn_mfma_f32_32x32x16_bf16(x2, b2, zero, 0, 0, 0);
        acc4(part, d1, d2);
    };

    // chunk window: 16 j-tiles starting at I0+1+16c (mod nT; max raw 766)
    int js = I0 + 1 + 16 * c;
    int len1 = nT - js; if (len1 > 16) len1 = 16; if (len1 < 0) len1 = 0;
    int len2 = 16 - len1;
    if (len1 > 0) run(js, len1);
    if (len2 > 0) run(js + len1 - nT, len2);

    if (c == 0) {
        one_tile(corrP, a1_0, a2_0, I0);                    // +T(I0,I0)
        one_tile(corrM, a1_1, a2_1, I0 + 1);                // -T(I1,I0+1)
    } else if (c == 15) {
        int v = I0 + 256; if (v >= nT) v -= nT;
        int y = I0 + 257; if (y >= nT) y -= nT;
        one_tile(corrM, a1_0, a2_0, v);                     // -T(I0,I0+256)
        one_tile(corrP, a1_1, a2_1, y);                     // +T(I1,I0+257)
    }

    float s = 2.0f * (partA.x + partA.y + partA.z + partA.w)
            + (corrP.x + corrP.y + corrP.z + corrP.w)
            - (corrM.x + corrM.y + corrM.z + corrM.w);
#pragma unroll
    for (int off = 32; off > 0; off >>= 1) s += __shfl_down(s, off, 64);
    if (lane == 0) wsum[wv] = s;
    __syncthreads();
    if (tid == 0) {
        float t = wsum[0] + wsum[1] + wsum[2] + wsum[3];
        atomicAdd(out, t);
    }
}

extern "C" void kernel_launch(void* const* d_in, const int* in_sizes, int n_in,
                              void* d_out, int out_size, void* d_ws, size_t ws_size,
                              hipStream_t stream) {
    const float* verts = (const float*)d_in[0];   // (V,3) f32
    const float* tnorm = (const float*)d_in[1];   // (M,3) f32
    const float* tcent = (const float*)d_in[2];   // (M,3) f32
    const int*   sidx  = (const int*)d_in[3];     // (N,3) i32

    int M = in_sizes[1] / 3;
    int N = in_sizes[3] / 3;
    int P = N + M;                                // 16384

    unsigned short* ws = (unsigned short*)d_ws;   // A1|A2|B1|B2 = 4 MB
    float* out = (float*)d_out;

    int bblocks = (P + 255) / 256;
    dc_pack<<<bblocks, 256, 0, stream>>>(verts, tnorm, tcent, sidx, ws, out, N, M);

    // 256 row-pairs x 16 chunks = 4096 waves = 1024 blocks (4/CU, one batch)
    dc_pair_mfma<<<1024, 256, 0, stream>>>(ws, out, P);
}

// Round 10
// 83.127 us; speedup vs baseline: 1.2001x; 1.0075x over previous
//
#include <hip/hip_runtime.h>

typedef short bf16x8 __attribute__((ext_vector_type(8)));
typedef float f32x16 __attribute__((ext_vector_type(16)));

// round-to-nearest-even fp32 -> bf16 (bits)
static __device__ __forceinline__ unsigned short f2bf(float x) {
    unsigned u = __builtin_bit_cast(unsigned, x);
    unsigned r = (u + 0x7FFFu + ((u >> 16) & 1u)) >> 16;
    return (unsigned short)r;
}
static __device__ __forceinline__ float bf2f(unsigned short h) {
    unsigned u = (unsigned)h << 16;
    return __builtin_bit_cast(float, u);
}

// Workspace (shorts): A1[P*16] | A2[P*16] | B1[P*16] | B2[P*16]

// Kernel 1: per point p build MFMA K-vectors (bf16, hi/lo split) for two grams:
//   gram1: denom = 1 + s_i + s_j - 2<c_i,c_j>;  gram2: dot = <n_i,n_j>
// 32x32x16 fragment layout (verified R5-R9, absmax 0.0): point p -> tile=p>>5,
// m=p&31; k0..7 chunk -> lane m, k8..15 -> lane 32+m.
// Targets carry NEGATED normals (folds e_ss - 2 e_st + e_tt into one sum).
__global__ void dc_pack(const float* __restrict__ verts,
                        const float* __restrict__ tnorm,
                        const float* __restrict__ tcent,
                        const int* __restrict__ idx,
                        unsigned short* __restrict__ ws,
                        float* __restrict__ out,
                        int N, int M) {
    int p = blockIdx.x * blockDim.x + threadIdx.x;
    if (p == 0) out[0] = 0.0f;
    int P = N + M;
    if (p >= P) return;

    float cx, cy, cz, nx, ny, nz;
    if (p < N) {
        int i0 = idx[3 * p + 0], i1 = idx[3 * p + 1], i2 = idx[3 * p + 2];
        float ax = verts[3 * i0], ay = verts[3 * i0 + 1], az = verts[3 * i0 + 2];
        float bx = verts[3 * i1], by = verts[3 * i1 + 1], bz = verts[3 * i1 + 2];
        float qx = verts[3 * i2], qy = verts[3 * i2 + 1], qz = verts[3 * i2 + 2];
        float ux = ax - bx, uy = ay - by, uz = az - bz;
        float vx = qx - bx, vy = qy - by, vz = qz - bz;
        nx = 0.5f * (uy * vz - uz * vy);
        ny = 0.5f * (uz * vx - ux * vz);
        nz = 0.5f * (ux * vy - uy * vx);
        cx = (ax + bx + qx) * (1.0f / 3.0f);
        cy = (ay + by + qy) * (1.0f / 3.0f);
        cz = (az + bz + qz) * (1.0f / 3.0f);
    } else {
        int t = p - N;
        cx = tcent[3 * t]; cy = tcent[3 * t + 1]; cz = tcent[3 * t + 2];
        nx = -tnorm[3 * t]; ny = -tnorm[3 * t + 1]; nz = -tnorm[3 * t + 2];
    }

    unsigned short chx = f2bf(cx), chy = f2bf(cy), chz = f2bf(cz);
    unsigned short clx = f2bf(cx - bf2f(chx));
    unsigned short cly = f2bf(cy - bf2f(chy));
    unsigned short clz = f2bf(cz - bf2f(chz));
    unsigned short nhx = f2bf(nx), nhy = f2bf(ny), nhz = f2bf(nz);
    unsigned short nlx = f2bf(nx - bf2f(nhx));
    unsigned short nly = f2bf(ny - bf2f(nhy));
    unsigned short nlz = f2bf(nz - bf2f(nhz));
    float ex = bf2f(chx) + bf2f(clx);
    float ey = bf2f(chy) + bf2f(cly);
    float ez = bf2f(chz) + bf2f(clz);
    float s = ex * ex + ey * ey + ez * ez;
    unsigned short sh = f2bf(s), sl = f2bf(s - bf2f(sh));
    unsigned short m2hx = f2bf(-2.0f * bf2f(chx)), m2hy = f2bf(-2.0f * bf2f(chy)), m2hz = f2bf(-2.0f * bf2f(chz));
    unsigned short m2lx = f2bf(-2.0f * bf2f(clx)), m2ly = f2bf(-2.0f * bf2f(cly)), m2lz = f2bf(-2.0f * bf2f(clz));
    const unsigned short one = 0x3F80;

    __align__(16) unsigned short A1v[16] = {
        m2hx, m2hy, m2hz,  m2hx, m2hy, m2hz,  m2lx, m2ly, m2lz,
        sh, sl,  one, one,  one,  0, 0 };
    __align__(16) unsigned short B1v[16] = {
        chx, chy, chz,  clx, cly, clz,  chx, chy, chz,
        one, one,  sh, sl,  one,  0, 0 };
    __align__(16) unsigned short A2v[16] = {
        nhx, nhy, nhz,  nhx, nhy, nhz,  nlx, nly, nlz,
        0, 0, 0, 0, 0, 0, 0 };
    __align__(16) unsigned short B2v[16] = {
        nhx, nhy, nhz,  nlx, nly, nlz,  nhx, nhy, nhz,
        0, 0, 0, 0, 0, 0, 0 };

    size_t arr = (size_t)P * 16;
    unsigned short* A1 = ws;
    unsigned short* A2 = ws + arr;
    unsigned short* B1 = ws + 2 * arr;
    unsigned short* B2 = ws + 3 * arr;

    int tile = p >> 5, m = p & 31;
    size_t lo = ((size_t)tile * 64 + m) * 8;       // k0..7 -> lane m
    size_t hi = lo + 32 * 8;                       // k8..15 -> lane 32+m

    *(uint4*)(A1 + lo) = *(const uint4*)&A1v[0];
    *(uint4*)(A1 + hi) = *(const uint4*)&A1v[8];
    *(uint4*)(A2 + lo) = *(const uint4*)&A2v[0];
    *(uint4*)(A2 + hi) = *(const uint4*)&A2v[8];
    *(uint4*)(B1 + lo) = *(const uint4*)&B1v[0];
    *(uint4*)(B1 + hi) = *(const uint4*)&B1v[8];
    *(uint4*)(B2 + lo) = *(const uint4*)&B2v[0];
    *(uint4*)(B2 + hi) = *(const uint4*)&B2v[8];
}

// 4-way batched reciprocal: sum of 4 x/a terms via 1 rcp (trans-pipe 4x cut).
static __device__ __forceinline__ void acc4(float4& part, const f32x16& d1, const f32x16& d2) {
#pragma unroll
    for (int g = 0; g < 4; ++g) {
        const int r = 4 * g;
        float p01 = d1[r] * d1[r + 1];
        float p23 = d1[r + 2] * d1[r + 3];
        float n01 = fmaf(d2[r], d1[r + 1], d2[r + 1] * d1[r]);
        float n23 = fmaf(d2[r + 2], d1[r + 3], d2[r + 3] * d1[r + 2]);
        float t   = p01 * p23;
        float num = fmaf(n01, p23, n23 * p01);
        (&part.x)[g] = fmaf(num, __builtin_amdgcn_rcpf(t), (&part.x)[g]);
    }
}

// Kernel 2: row-paired circular symmetric sweep, hand-pipelined.
// Rows (I0=2rp, I1=I0+1) share j-window W=[I0+1, I0+256] (mod nT). Exact:
//   contrib(rp) = 2*sum_W [T(I0,j)+T(I1,j)]
//               + T(I0,I0) + T(I1,I0+257) - T(I0,I0+256) - T(I1,I0+1)
// Hot loop is unroll-2 with two NAMED buffer sets; loads for tile t+1 sit at
// the TOP of the half that processes tile t (~400 cyc of MFMA+VALU between
// issue and use), no register copies -- the scheduler cannot sink the loads
// to the loop bottom (the R9 failure mode that exposed L2 latency per iter).
// Wrap is branchless wave-uniform SALU. 1024 blocks = 4/CU, one batch.
__global__ __launch_bounds__(256, 4) void dc_pair_mfma(
    const unsigned short* __restrict__ ws, float* __restrict__ out, int P) {
    __shared__ float wsum[4];

    const int nT = P >> 5;                     // 512
    size_t arr = (size_t)P * 16;
    const unsigned short* A1 = ws;
    const unsigned short* A2 = ws + arr;
    const unsigned short* B1 = ws + 2 * arr;
    const unsigned short* B2 = ws + 3 * arr;

    int tid = threadIdx.x;
    int lane = tid & 63, wv = tid >> 6;
    int gi = blockIdx.x * 4 + wv;              // 0..4095
    int rp = gi >> 4, c = gi & 15;
    int I0 = 2 * rp, I1 = I0 + 1;

    const size_t lo = (size_t)lane * 8;

    bf16x8 a1_0 = *(const bf16x8*)(A1 + (size_t)I0 * 512 + lo);
    bf16x8 a2_0 = *(const bf16x8*)(A2 + (size_t)I0 * 512 + lo);
    bf16x8 a1_1 = *(const bf16x8*)(A1 + (size_t)I1 * 512 + lo);
    bf16x8 a2_1 = *(const bf16x8*)(A2 + (size_t)I1 * 512 + lo);

    const f32x16 zero = {0.f,0.f,0.f,0.f,0.f,0.f,0.f,0.f,0.f,0.f,0.f,0.f,0.f,0.f,0.f,0.f};
    float4 partA = make_float4(0.f, 0.f, 0.f, 0.f);
    float4 corrP = make_float4(0.f, 0.f, 0.f, 0.f);
    float4 corrM = make_float4(0.f, 0.f, 0.f, 0.f);

    auto wrap = [&](int j) -> size_t {
        return (size_t)(j >= nT ? j - nT : j) * 512;   // wave-uniform SALU
    };
    auto process = [&](const bf16x8& b1, const bf16x8& b2) {
        f32x16 d1 = __builtin_amdgcn_mfma_f32_32x32x16_bf16(a1_0, b1, zero, 0, 0, 0);
        f32x16 d2 = __builtin_amdgcn_mfma_f32_32x32x16_bf16(a2_0, b2, zero, 0, 0, 0);
        f32x16 e1 = __builtin_amdgcn_mfma_f32_32x32x16_bf16(a1_1, b1, zero, 0, 0, 0);
        f32x16 e2 = __builtin_amdgcn_mfma_f32_32x32x16_bf16(a2_1, b2, zero, 0, 0, 0);
        acc4(partA, d1, d2);
        acc4(partA, e1, e2);
    };
    auto one_tile = [&](float4& part, const bf16x8& x1, const bf16x8& x2, int jm) {
        const bf16x8 b1 = *(const bf16x8*)(B1 + (size_t)jm * 512 + lo);
        const bf16x8 b2 = *(const bf16x8*)(B2 + (size_t)jm * 512 + lo);
        f32x16 d1 = __builtin_amdgcn_mfma_f32_32x32x16_bf16(x1, b1, zero, 0, 0, 0);
        f32x16 d2 = __builtin_amdgcn_mfma_f32_32x32x16_bf16(x2, b2, zero, 0, 0, 0);
        acc4(part, d1, d2);
    };

    // chunk window: 16 j-tiles starting at I0+1+16c (mod nT; raw max 751+16)
    int js = I0 + 1 + 16 * c;

    // software pipeline: bufA holds tile t, bufB tile t+1; loads at half-tops.
    bf16x8 bA1 = *(const bf16x8*)(B1 + wrap(js) + lo);
    bf16x8 bA2 = *(const bf16x8*)(B2 + wrap(js) + lo);
#pragma unroll 1
    for (int it = 0; it < 16; it += 2) {
        size_t o1 = wrap(js + it + 1);
        bf16x8 bB1 = *(const bf16x8*)(B1 + o1 + lo);   // load t+1 (top)
        bf16x8 bB2 = *(const bf16x8*)(B2 + o1 + lo);
        process(bA1, bA2);                             // tile t
        size_t o2 = wrap(js + it + 2);                 // t+2 (last round: valid
        bA1 = *(const bf16x8*)(B1 + o2 + lo);          //  wrapped tile, unused)
        bA2 = *(const bf16x8*)(B2 + o2 + lo);
        process(bB1, bB2);                             // tile t+1
    }

    if (c == 0) {
        one_tile(corrP, a1_0, a2_0, I0);                    // +T(I0,I0)
        one_tile(corrM, a1_1, a2_1, I0 + 1);                // -T(I1,I0+1)
    } else if (c == 15) {
        int v = I0 + 256; if (v >= nT) v -= nT;
        int y = I0 + 257; if (y >= nT) y -= nT;
        one_tile(corrM, a1_0, a2_0, v);                     // -T(I0,I0+256)
        one_tile(corrP, a1_1, a2_1, y);                     // +T(I1,I0+257)
    }

    float s = 2.0f * (partA.x + partA.y + partA.z + partA.w)
            + (corrP.x + corrP.y + corrP.z + corrP.w)
            - (corrM.x + corrM.y + corrM.z + corrM.w);
#pragma unroll
    for (int off = 32; off > 0; off >>= 1) s += __shfl_down(s, off, 64);
    if (lane == 0) wsum[wv] = s;
    __syncthreads();
    if (tid == 0) {
        float t = wsum[0] + wsum[1] + wsum[2] + wsum[3];
        atomicAdd(out, t);
    }
}

extern "C" void kernel_launch(void* const* d_in, const int* in_sizes, int n_in,
                              void* d_out, int out_size, void* d_ws, size_t ws_size,
                              hipStream_t stream) {
    const float* verts = (const float*)d_in[0];   // (V,3) f32
    const float* tnorm = (const float*)d_in[1];   // (M,3) f32
    const float* tcent = (const float*)d_in[2];   // (M,3) f32
    const int*   sidx  = (const int*)d_in[3];     // (N,3) i32

    int M = in_sizes[1] / 3;
    int N = in_sizes[3] / 3;
    int P = N + M;                                // 16384

    unsigned short* ws = (unsigned short*)d_ws;   // A1|A2|B1|B2 = 4 MB
    float* out = (float*)d_out;

    int bblocks = (P + 255) / 256;
    dc_pack<<<bblocks, 256, 0, stream>>>(verts, tnorm, tcent, sidx, ws, out, N, M);

    // 256 row-pairs x 16 chunks = 4096 waves = 1024 blocks (4/CU, one batch)
    dc_pair_mfma<<<1024, 256, 0, stream>>>(ws, out, P);
}